// Round 1
// baseline (602.744 us; speedup 1.0000x reference)
//
#include <hip/hip_runtime.h>
#include <cstdint>
#include <cstddef>

#define NN 8192
#define FI 128
#define FO 128
#define NCH 4

typedef __attribute__((ext_vector_type(8))) __bf16 bf16x8;
typedef __attribute__((ext_vector_type(8))) short short8;
typedef __attribute__((ext_vector_type(4))) float f32x4;

static __device__ __forceinline__ f32x4 mfma16(bf16x8 a, bf16x8 b, f32x4 c) {
  return __builtin_amdgcn_mfma_f32_16x16x32_bf16(a, b, c, 0, 0, 0);
}

static __device__ __forceinline__ unsigned short f2bfu(float f) {
  union { __bf16 h; unsigned short u; } cv;
  cv.h = (__bf16)f;
  return cv.u;
}

static __device__ __forceinline__ bf16x8 cvt8(float4 a, float4 b) {
  bf16x8 v;
  v[0] = (__bf16)a.x; v[1] = (__bf16)a.y; v[2] = (__bf16)a.z; v[3] = (__bf16)a.w;
  v[4] = (__bf16)b.x; v[5] = (__bf16)b.y; v[6] = (__bf16)b.z; v[7] = (__bf16)b.w;
  return v;
}

// ---------------------------------------------------------------------------
// Pack X (fp32 [8192][128]) into bf16 MFMA-B-fragment order:
// PX frag index g = nt*256 + kk  (nt = col-tile 0..7, kk = k-step 0..255)
// lane l of frag g holds X[kk*32 + (l>>4)*8 + j][nt*16 + (l&15)], j=0..7,
// stored as 8 contiguous bf16 (16 B) at PX + (g*64 + l)*8.
// ---------------------------------------------------------------------------
__global__ void gcs_pack_x(const float* __restrict__ X, unsigned short* __restrict__ PX) {
  int gid = blockIdx.x * 256 + threadIdx.x;   // 131072 threads
  int l   = gid & 63;
  int g   = gid >> 6;                          // 0..2047
  int kk  = g & 255;
  int nt  = g >> 8;
  int col = nt * 16 + (l & 15);
  int k0  = kk * 32 + (l >> 4) * 8;
  unsigned int w[4];
#pragma unroll
  for (int p = 0; p < 4; ++p) {
    unsigned short lo = f2bfu(X[(size_t)(k0 + 2 * p) * FI + col]);
    unsigned short hi = f2bfu(X[(size_t)(k0 + 2 * p + 1) * FI + col]);
    w[p] = (unsigned int)lo | ((unsigned int)hi << 16);
  }
  uint4 v = make_uint4(w[0], w[1], w[2], w[3]);
  ((uint4*)PX)[g * 64 + l] = v;
}

// ---------------------------------------------------------------------------
// Pack adj_W (fp32 [4][128][128]) into bf16 B-fragment order:
// frag index g = c*32 + ot*4 + ks ; lane l holds
// adj_W[c][ks*32 + (l>>4)*8 + j][ot*16 + (l&15)]
// ---------------------------------------------------------------------------
__global__ void gcs_pack_w(const float* __restrict__ AW, unsigned short* __restrict__ PW) {
  int gid = blockIdx.x * 256 + threadIdx.x;   // 8192 threads
  int l   = gid & 63;
  int g   = gid >> 6;                          // 0..127
  int ks  = g & 3;
  int ot  = (g >> 2) & 7;
  int c   = g >> 5;
  const float* base = AW + (size_t)c * FI * FO;
  int col = ot * 16 + (l & 15);
  int k0  = ks * 32 + (l >> 4) * 8;
  unsigned int w[4];
#pragma unroll
  for (int p = 0; p < 4; ++p) {
    unsigned short lo = f2bfu(base[(k0 + 2 * p) * FO + col]);
    unsigned short hi = f2bfu(base[(k0 + 2 * p + 1) * FO + col]);
    w[p] = (unsigned int)lo | ((unsigned int)hi << 16);
  }
  uint4 v = make_uint4(w[0], w[1], w[2], w[3]);
  ((uint4*)PW)[g * 64 + l] = v;
}

// ---------------------------------------------------------------------------
// acc[n][o] = b[o] + sum_f X[n][f] * W[f][o]   (fp32, exact path)
// ---------------------------------------------------------------------------
__global__ void gcs_xpart(const float* __restrict__ X, const float* __restrict__ W,
                          const float* __restrict__ b, float* __restrict__ acc) {
  int gid = blockIdx.x * 256 + threadIdx.x;   // 8192*128 threads
  int n = gid >> 7;
  int o = gid & 127;
  const float4* Xr = (const float4*)(X + (size_t)n * FI);
  float s = b[o];
#pragma unroll 4
  for (int f4 = 0; f4 < FI / 4; ++f4) {
    float4 xv = Xr[f4];
    s += xv.x * W[(f4 * 4 + 0) * FO + o];
    s += xv.y * W[(f4 * 4 + 1) * FO + o];
    s += xv.z * W[(f4 * 4 + 2) * FO + o];
    s += xv.w * W[(f4 * 4 + 3) * FO + o];
  }
  acc[gid] = s;
}

// ---------------------------------------------------------------------------
// Main: per (row-tile of 32, channel): AX = A_c[rows,:] @ X (bf16 MFMA,
// fp32 accum), then relu(AX @ adjW_c) atomically added into acc.
// 4 waves; wave w owns f-cols / o-cols [w*32, w*32+32).
// ---------------------------------------------------------------------------
__global__ void __launch_bounds__(256, 4)
gcs_main(const float* __restrict__ adjs, const unsigned short* __restrict__ PX,
         const unsigned short* __restrict__ PW, float* __restrict__ acc) {
  const int rt  = blockIdx.x;      // 0..255 row tile
  const int c   = blockIdx.y;      // 0..3 channel
  const int tid = threadIdx.x;
  const int w   = tid >> 6;        // wave 0..3
  const int l   = tid & 63;
  const int lr  = l & 15;          // row-in-tile (A) / col (B)
  const int lk  = l >> 4;          // k-group 0..3

  // swizzled bf16 AX tile [32][128]: byte = row*256 + col*2, ^ ((row&7)<<4)
  __shared__ unsigned short AXs[32 * 128];

  const float* A   = adjs + (size_t)c * NN * NN;
  const float* pA0 = A + (size_t)(rt * 32 + lr) * NN + lk * 8;
  const float* pA1 = pA0 + (size_t)16 * NN;

  const bf16x8* pX0 = (const bf16x8*)PX + (size_t)((w * 2 + 0) * 256) * 64 + l;
  const bf16x8* pX1 = (const bf16x8*)PX + (size_t)((w * 2 + 1) * 256) * 64 + l;

  f32x4 acc00 = {}, acc01 = {}, acc10 = {}, acc11 = {};

#pragma unroll 2
  for (int kk = 0; kk < NN / 32; ++kk) {
    float4 a0a = *(const float4*)(pA0 + (size_t)kk * 32);
    float4 a0b = *(const float4*)(pA0 + (size_t)kk * 32 + 4);
    float4 a1a = *(const float4*)(pA1 + (size_t)kk * 32);
    float4 a1b = *(const float4*)(pA1 + (size_t)kk * 32 + 4);
    bf16x8 B0 = pX0[(size_t)kk * 64];
    bf16x8 B1 = pX1[(size_t)kk * 64];
    bf16x8 A0 = cvt8(a0a, a0b);
    bf16x8 A1 = cvt8(a1a, a1b);
    acc00 = mfma16(A0, B0, acc00);
    acc01 = mfma16(A0, B1, acc01);
    acc10 = mfma16(A1, B0, acc10);
    acc11 = mfma16(A1, B1, acc11);
  }

  // C/D layout: col = l&15, row = (l>>4)*4 + r  -> write AX to swizzled LDS
#pragma unroll
  for (int mt = 0; mt < 2; ++mt) {
#pragma unroll
    for (int ntl = 0; ntl < 2; ++ntl) {
      f32x4 v = (mt == 0) ? (ntl == 0 ? acc00 : acc01)
                          : (ntl == 0 ? acc10 : acc11);
      int col = (w * 2 + ntl) * 16 + lr;
#pragma unroll
      for (int r = 0; r < 4; ++r) {
        int row  = mt * 16 + lk * 4 + r;
        int byte = (row * 256 + col * 2) ^ ((row & 7) << 4);
        *(unsigned short*)((char*)AXs + byte) = f2bfu(v[r]);
      }
    }
  }
  __syncthreads();

  // Projection: relu( AX[32x128] @ adjW_c[128x128] ), K = 128 (4 k-steps)
  f32x4 p00 = {}, p01 = {}, p10 = {}, p11 = {};
  const bf16x8* pWc = (const bf16x8*)PW + (size_t)(c * 32) * 64;
#pragma unroll
  for (int ks = 0; ks < 4; ++ks) {
    int fb = (ks * 32 + lk * 8) * 2;   // byte offset of 8 bf16 along f
    int row0 = lr, row1 = 16 + lr;
    int byte0 = (row0 * 256 + fb) ^ ((row0 & 7) << 4);
    int byte1 = (row1 * 256 + fb) ^ ((row1 & 7) << 4);
    bf16x8 a0 = __builtin_bit_cast(bf16x8, *(const short8*)((const char*)AXs + byte0));
    bf16x8 a1 = __builtin_bit_cast(bf16x8, *(const short8*)((const char*)AXs + byte1));
    bf16x8 b0 = pWc[(size_t)((w * 2 + 0) * 4 + ks) * 64 + l];
    bf16x8 b1 = pWc[(size_t)((w * 2 + 1) * 4 + ks) * 64 + l];
    p00 = mfma16(a0, b0, p00);
    p01 = mfma16(a0, b1, p01);
    p10 = mfma16(a1, b0, p10);
    p11 = mfma16(a1, b1, p11);
  }

  // relu per channel, then atomic accumulate into acc (pre-loaded with x_part+b)
#pragma unroll
  for (int mt = 0; mt < 2; ++mt) {
#pragma unroll
    for (int otl = 0; otl < 2; ++otl) {
      f32x4 v = (mt == 0) ? (otl == 0 ? p00 : p01)
                          : (otl == 0 ? p10 : p11);
      int o = (w * 2 + otl) * 16 + lr;
#pragma unroll
      for (int r = 0; r < 4; ++r) {
        int row_g = rt * 32 + mt * 16 + lk * 4 + r;
        float x = fmaxf(v[r], 0.0f);
        atomicAdd(&acc[(size_t)row_g * FO + o], x);
      }
    }
  }
}

// ---------------------------------------------------------------------------
// out = relu(acc)
// ---------------------------------------------------------------------------
__global__ void gcs_final(const float* __restrict__ acc, float* __restrict__ out) {
  int i = blockIdx.x * 256 + threadIdx.x;    // over float4s
  float4 v = ((const float4*)acc)[i];
  v.x = fmaxf(v.x, 0.0f);
  v.y = fmaxf(v.y, 0.0f);
  v.z = fmaxf(v.z, 0.0f);
  v.w = fmaxf(v.w, 0.0f);
  ((float4*)out)[i] = v;
}

extern "C" void kernel_launch(void* const* d_in, const int* in_sizes, int n_in,
                              void* d_out, int out_size, void* d_ws, size_t ws_size,
                              hipStream_t stream) {
  const float* X    = (const float*)d_in[0];   // [8192][128]
  const float* adjs = (const float*)d_in[1];   // [4][8192][8192]
  const float* W    = (const float*)d_in[2];   // [128][128]
  const float* AW   = (const float*)d_in[3];   // [4][128][128]
  const float* b    = (const float*)d_in[4];   // [128]
  float* out = (float*)d_out;

  char* ws = (char*)d_ws;
  float*          accbuf = (float*)ws;                          // 4 MB
  unsigned short* PX     = (unsigned short*)(ws + (4u << 20));  // 2 MB
  unsigned short* PW     = (unsigned short*)(ws + (6u << 20));  // 128 KB

  hipLaunchKernelGGL(gcs_pack_x, dim3(512),     dim3(256), 0, stream, X, PX);
  hipLaunchKernelGGL(gcs_pack_w, dim3(32),      dim3(256), 0, stream, AW, PW);
  hipLaunchKernelGGL(gcs_xpart,  dim3(4096),    dim3(256), 0, stream, X, W, b, accbuf);
  hipLaunchKernelGGL(gcs_main,   dim3(256, 4),  dim3(256), 0, stream, adjs, PX, PW, accbuf);
  hipLaunchKernelGGL(gcs_final,  dim3(1024),    dim3(256), 0, stream, accbuf, out);
}

// Round 2
// 290.724 us; speedup vs baseline: 2.0732x; 2.0732x over previous
//
#include <hip/hip_runtime.h>
#include <cstdint>
#include <cstddef>

#define NN 8192
#define FI 128
#define FO 128
#define NCH 4
#define BK 512            // K-tile staged in LDS
#define NT (NN / BK)      // 16 K-tiles
#define SUBS (BK / 32)    // 16 MFMA k-steps per tile

typedef __attribute__((ext_vector_type(8))) __bf16 bf16x8;
typedef __attribute__((ext_vector_type(8))) short short8;
typedef __attribute__((ext_vector_type(4))) float f32x4;

static __device__ __forceinline__ f32x4 mfma16(bf16x8 a, bf16x8 b, f32x4 c) {
  return __builtin_amdgcn_mfma_f32_16x16x32_bf16(a, b, c, 0, 0, 0);
}

static __device__ __forceinline__ unsigned short f2bfu(float f) {
  union { __bf16 h; unsigned short u; } cv;
  cv.h = (__bf16)f;
  return cv.u;
}

static __device__ __forceinline__ bf16x8 cvt8(float4 a, float4 b) {
  bf16x8 v;
  v[0] = (__bf16)a.x; v[1] = (__bf16)a.y; v[2] = (__bf16)a.z; v[3] = (__bf16)a.w;
  v[4] = (__bf16)b.x; v[5] = (__bf16)b.y; v[6] = (__bf16)b.z; v[7] = (__bf16)b.w;
  return v;
}

// ---------------------------------------------------------------------------
// Pack X (fp32 [8192][128]) into bf16 MFMA-B-fragment order:
// frag g = nt*256 + kk ; lane l holds X[kk*32 + (l>>4)*8 + j][nt*16 + (l&15)]
// ---------------------------------------------------------------------------
__global__ void gcs_pack_x(const float* __restrict__ X, unsigned short* __restrict__ PX) {
  int gid = blockIdx.x * 256 + threadIdx.x;   // 131072 threads
  int l   = gid & 63;
  int g   = gid >> 6;                          // 0..2047
  int kk  = g & 255;
  int nt  = g >> 8;
  int col = nt * 16 + (l & 15);
  int k0  = kk * 32 + (l >> 4) * 8;
  unsigned int w[4];
#pragma unroll
  for (int p = 0; p < 4; ++p) {
    unsigned short lo = f2bfu(X[(size_t)(k0 + 2 * p) * FI + col]);
    unsigned short hi = f2bfu(X[(size_t)(k0 + 2 * p + 1) * FI + col]);
    w[p] = (unsigned int)lo | ((unsigned int)hi << 16);
  }
  uint4 v = make_uint4(w[0], w[1], w[2], w[3]);
  ((uint4*)PX)[g * 64 + l] = v;
}

// ---------------------------------------------------------------------------
// Pack adj_W (fp32 [4][128][128]) into bf16 B-fragment order:
// frag g = c*32 + ot*4 + ks ; lane l holds adj_W[c][ks*32+(l>>4)*8+j][ot*16+(l&15)]
// ---------------------------------------------------------------------------
__global__ void gcs_pack_w(const float* __restrict__ AW, unsigned short* __restrict__ PW) {
  int gid = blockIdx.x * 256 + threadIdx.x;   // 8192 threads
  int l   = gid & 63;
  int g   = gid >> 6;                          // 0..127
  int ks  = g & 3;
  int ot  = (g >> 2) & 7;
  int c   = g >> 5;
  const float* base = AW + (size_t)c * FI * FO;
  int col = ot * 16 + (l & 15);
  int k0  = ks * 32 + (l >> 4) * 8;
  unsigned int w[4];
#pragma unroll
  for (int p = 0; p < 4; ++p) {
    unsigned short lo = f2bfu(base[(k0 + 2 * p) * FO + col]);
    unsigned short hi = f2bfu(base[(k0 + 2 * p + 1) * FO + col]);
    w[p] = (unsigned int)lo | ((unsigned int)hi << 16);
  }
  uint4 v = make_uint4(w[0], w[1], w[2], w[3]);
  ((uint4*)PW)[g * 64 + l] = v;
}

// ---------------------------------------------------------------------------
// acc[n][o] = b[o] + sum_f X[n][f] * W[f][o]   (fp32, exact path)
// ---------------------------------------------------------------------------
__global__ void gcs_xpart(const float* __restrict__ X, const float* __restrict__ W,
                          const float* __restrict__ b, float* __restrict__ acc) {
  int gid = blockIdx.x * 256 + threadIdx.x;   // 8192*128 threads
  int n = gid >> 7;
  int o = gid & 127;
  const float4* Xr = (const float4*)(X + (size_t)n * FI);
  float s = b[o];
#pragma unroll 4
  for (int f4 = 0; f4 < FI / 4; ++f4) {
    float4 xv = Xr[f4];
    s += xv.x * W[(f4 * 4 + 0) * FO + o];
    s += xv.y * W[(f4 * 4 + 1) * FO + o];
    s += xv.z * W[(f4 * 4 + 2) * FO + o];
    s += xv.w * W[(f4 * 4 + 3) * FO + o];
  }
  acc[gid] = s;
}

// ---------------------------------------------------------------------------
// Main: per (32-row tile, channel). Per K-tile of 512: cooperative burst-load
// of A (2KB contiguous per row), fp32->bf16 once, XOR-swizzled LDS; MFMA
// fragments read from LDS. Then relu(AX @ adjW_c) atomic-added into acc.
// LDS = 32KB Abuf + 8KB AXs = 40KB -> 4 blocks/CU.
// ---------------------------------------------------------------------------
__global__ void __launch_bounds__(256, 4)
gcs_main(const float* __restrict__ adjs, const unsigned short* __restrict__ PX,
         const unsigned short* __restrict__ PW, float* __restrict__ acc) {
  const int rt  = blockIdx.x;      // 0..255 row tile
  const int c   = blockIdx.y;      // 0..3 channel
  const int tid = threadIdx.x;
  const int w   = tid >> 6;        // wave 0..3
  const int l   = tid & 63;
  const int lr  = l & 15;
  const int lk  = l >> 4;

  // A tile, bf16, row-major [32][512]; byte = row*1024 + k*2, ^((row&7)<<4)
  __shared__ unsigned short Abuf[32 * BK];
  // AX tile, bf16, [32][128]; byte = row*256 + col*2, ^((row&7)<<4)
  __shared__ unsigned short AXs[32 * 128];

  const float* Ab = adjs + (size_t)c * NN * NN + (size_t)(rt * 32) * NN;

  const char* pX0 = (const char*)PX + (size_t)((w * 2 + 0) * 256) * 1024 + l * 16;
  const char* pX1 = (const char*)PX + (size_t)((w * 2 + 1) * 256) * 1024 + l * 16;

  f32x4 acc00 = {}, acc01 = {}, acc10 = {}, acc11 = {};

  for (int t = 0; t < NT; ++t) {
    // ---- stage: wave w loads rows w*8..w*8+7, cols t*512..t*512+512 ----
    for (int g = 0; g < 2; ++g) {
      float4 v0[4], v1[4];
#pragma unroll
      for (int r = 0; r < 4; ++r) {
        int row = w * 8 + g * 4 + r;
        const float* p = Ab + (size_t)row * NN + t * BK + l * 8;
        v0[r] = *(const float4*)p;
        v1[r] = *(const float4*)(p + 4);
      }
#pragma unroll
      for (int r = 0; r < 4; ++r) {
        int row  = w * 8 + g * 4 + r;
        bf16x8 bv = cvt8(v0[r], v1[r]);
        int byte  = (row * (BK * 2) + l * 16) ^ ((row & 7) << 4);
        *(short8*)((char*)Abuf + byte) = __builtin_bit_cast(short8, bv);
      }
    }
    __syncthreads();

    // ---- compute: 16 k-substeps over this tile ----
#pragma unroll 4
    for (int s = 0; s < SUBS; ++s) {
      int kb = (s * 32 + lk * 8) * 2;           // byte offset along k
      int r0 = lr, r1 = 16 + lr;
      int b0 = (r0 * (BK * 2) + kb) ^ ((r0 & 7) << 4);
      int b1 = (r1 * (BK * 2) + kb) ^ ((r1 & 7) << 4);
      bf16x8 A0 = __builtin_bit_cast(bf16x8, *(const short8*)((const char*)Abuf + b0));
      bf16x8 A1 = __builtin_bit_cast(bf16x8, *(const short8*)((const char*)Abuf + b1));
      int kkG = t * SUBS + s;
      bf16x8 B0 = __builtin_bit_cast(bf16x8, *(const short8*)(pX0 + (size_t)kkG * 1024));
      bf16x8 B1 = __builtin_bit_cast(bf16x8, *(const short8*)(pX1 + (size_t)kkG * 1024));
      acc00 = mfma16(A0, B0, acc00);
      acc01 = mfma16(A0, B1, acc01);
      acc10 = mfma16(A1, B0, acc10);
      acc11 = mfma16(A1, B1, acc11);
    }
    __syncthreads();
  }

  // ---- AX -> swizzled LDS (bf16) ----
#pragma unroll
  for (int mt = 0; mt < 2; ++mt) {
#pragma unroll
    for (int ntl = 0; ntl < 2; ++ntl) {
      f32x4 v = (mt == 0) ? (ntl == 0 ? acc00 : acc01)
                          : (ntl == 0 ? acc10 : acc11);
      int col = (w * 2 + ntl) * 16 + lr;
#pragma unroll
      for (int r = 0; r < 4; ++r) {
        int row  = mt * 16 + lk * 4 + r;
        int byte = (row * 256 + col * 2) ^ ((row & 7) << 4);
        *(unsigned short*)((char*)AXs + byte) = f2bfu(v[r]);
      }
    }
  }
  __syncthreads();

  // ---- projection: relu( AX[32x128] @ adjW_c[128x128] ) ----
  f32x4 p00 = {}, p01 = {}, p10 = {}, p11 = {};
  const bf16x8* pWc = (const bf16x8*)PW + (size_t)(c * 32) * 64;
#pragma unroll
  for (int ks = 0; ks < 4; ++ks) {
    int fb = (ks * 32 + lk * 8) * 2;
    int row0 = lr, row1 = 16 + lr;
    int byte0 = (row0 * 256 + fb) ^ ((row0 & 7) << 4);
    int byte1 = (row1 * 256 + fb) ^ ((row1 & 7) << 4);
    bf16x8 a0 = __builtin_bit_cast(bf16x8, *(const short8*)((const char*)AXs + byte0));
    bf16x8 a1 = __builtin_bit_cast(bf16x8, *(const short8*)((const char*)AXs + byte1));
    bf16x8 b0 = pWc[(size_t)((w * 2 + 0) * 4 + ks) * 64 + l];
    bf16x8 b1 = pWc[(size_t)((w * 2 + 1) * 4 + ks) * 64 + l];
    p00 = mfma16(a0, b0, p00);
    p01 = mfma16(a0, b1, p01);
    p10 = mfma16(a1, b0, p10);
    p11 = mfma16(a1, b1, p11);
  }

  // ---- relu per channel, atomic accumulate ----
#pragma unroll
  for (int mt = 0; mt < 2; ++mt) {
#pragma unroll
    for (int otl = 0; otl < 2; ++otl) {
      f32x4 v = (mt == 0) ? (otl == 0 ? p00 : p01)
                          : (otl == 0 ? p10 : p11);
      int o = (w * 2 + otl) * 16 + lr;
#pragma unroll
      for (int r = 0; r < 4; ++r) {
        int row_g = rt * 32 + mt * 16 + lk * 4 + r;
        float x = fmaxf(v[r], 0.0f);
        atomicAdd(&acc[(size_t)row_g * FO + o], x);
      }
    }
  }
}

// ---------------------------------------------------------------------------
// out = relu(acc)
// ---------------------------------------------------------------------------
__global__ void gcs_final(const float* __restrict__ acc, float* __restrict__ out) {
  int i = blockIdx.x * 256 + threadIdx.x;    // over float4s
  float4 v = ((const float4*)acc)[i];
  v.x = fmaxf(v.x, 0.0f);
  v.y = fmaxf(v.y, 0.0f);
  v.z = fmaxf(v.z, 0.0f);
  v.w = fmaxf(v.w, 0.0f);
  ((float4*)out)[i] = v;
}

extern "C" void kernel_launch(void* const* d_in, const int* in_sizes, int n_in,
                              void* d_out, int out_size, void* d_ws, size_t ws_size,
                              hipStream_t stream) {
  const float* X    = (const float*)d_in[0];   // [8192][128]
  const float* adjs = (const float*)d_in[1];   // [4][8192][8192]
  const float* W    = (const float*)d_in[2];   // [128][128]
  const float* AW   = (const float*)d_in[3];   // [4][128][128]
  const float* b    = (const float*)d_in[4];   // [128]
  float* out = (float*)d_out;

  char* ws = (char*)d_ws;
  float*          accbuf = (float*)ws;                          // 4 MB
  unsigned short* PX     = (unsigned short*)(ws + (4u << 20));  // 2 MB
  unsigned short* PW     = (unsigned short*)(ws + (6u << 20));  // 128 KB

  hipLaunchKernelGGL(gcs_pack_x, dim3(512),     dim3(256), 0, stream, X, PX);
  hipLaunchKernelGGL(gcs_pack_w, dim3(32),      dim3(256), 0, stream, AW, PW);
  hipLaunchKernelGGL(gcs_xpart,  dim3(4096),    dim3(256), 0, stream, X, W, b, accbuf);
  hipLaunchKernelGGL(gcs_main,   dim3(256, 4),  dim3(256), 0, stream, adjs, PX, PW, accbuf);
  hipLaunchKernelGGL(gcs_final,  dim3(1024),    dim3(256), 0, stream, accbuf, out);
}